// Round 14
// baseline (146.646 us; speedup 1.0000x reference)
//
#include <hip/hip_runtime.h>
#include <hip/hip_bf16.h>
#include <stdint.h>

// CapsuleLayer dynamic routing, MI355X. fp32 in/out.
// B=256, N=10, I=1152, D=16, K(Din)=8, ROUTINGS=3.
// R19: K1 merged back to 10-n blocks (n-split's occupancy rationale was
//      disproven in R17): block = (i-tile, b-quad), one x-load + one
//      prologue per 10 n (was per 2 n), W double-buffered in LDS
//      (2x8KB/wave), part0 epilogue once per block. ~10% fewer K1
//      instructions, 5x less x request traffic.
//      Route byte-identical to R16 (54us proven). R18 deferral (neutral)
//      dropped.

#define BN 256
#define NN 10
#define NH 5           // n per half-group (route)
#define II 1152
#define DD 16
#define KK 8
#define NT 18          // K1 i-tiles of 64

typedef unsigned short ushort_t;
typedef unsigned int uint_t;

__device__ __forceinline__ float bflo(uint_t u) {
    union { uint_t i; float f; } v; v.i = u << 16; return v.f;
}
__device__ __forceinline__ float bfhi(uint_t u) {
    union { uint_t i; float f; } v; v.i = u & 0xffff0000u; return v.f;
}
// packed f32x2 -> bf16x2 (RTNE) via v_cvt_pk_bf16_f32
__device__ __forceinline__ uint_t pkbf(float lo, float hi) {
    __hip_bfloat162 h = __float22bfloat162_rn(make_float2(lo, hi));
    uint_t u; __builtin_memcpy(&u, &h, sizeof(u)); return u;
}

// ---------------- K1 + sweep0 partials: 10-n blocks -------------------------
// block = (i-tile of 64, b-quad). 256 thr = 4 waves.
// lane = il*4+dq: thread owns (i = it*64 + wv*16 + il, d-quad dq), 4 b's,
// all 10 n. XCD swizzle keeps each XCD's W slice (~720 KB) L2-resident.
// W per (wave,n) = 8KB tile, double-buffered: stage(n+1) issued right after
// n's ds_reads complete; vmcnt(0) before n's reads waits only already-landed
// loads + small store drain (proven neutral, R18).
// Stage: 8 coalesced global_load_lds, linear LDS dest, XOR-swizzled source
// (involution lc^(row&7)); reads use swizzled STATIC offsets (rule #20).
// Butterfly leaves lane (il,dq) holding tile-sum of value j=il ->
// redn[wv][lane][n]; epilogue sums 4 waves -> part0 (640 values).
__global__ __launch_bounds__(256) void caps_uhat_s0(const float* __restrict__ xg,
                                                    const float* __restrict__ wg,
                                                    ushort_t* __restrict__ u,
                                                    float* __restrict__ part0,
                                                    int b0, int c4)
{
    __shared__ float wlds[4][2][2048];  // per-wave 2 x 8 KB W stage, 64 KB
    __shared__ float redn[4][64][NN];   // [wv][lane][n], 10 KB
    const int tid = threadIdx.x;
    const int lane = tid & 63, wv = tid >> 6;
    const int dq = lane & 3, il = lane >> 2;
    // grid = 18*c4, c4 multiple of 4 -> divisible by 8
    const int nb8 = gridDim.x >> 3;
    const int L   = (blockIdx.x & 7) * nb8 + (blockIdx.x >> 3);
    const int it  = L / c4;
    const int bl  = (L - it * c4) * 4;         // chunk-local b base (4 b's)
    const int i = it * 64 + wv * 16 + il;

    const bool h0 = (il & 1), h1 = (il >> 1) & 1, h2 = (il >> 2) & 1, h3 = (il >> 3) & 1;
    float* myred = &redn[wv][lane][0];
    const int lrow = lane >> 5, lc = lane & 31;
    const float4* wtile0 = (const float4*)(wg + (size_t)(it * 64 + wv * 16) * (DD * KK));

    // stage n's 8KB wave-tile into buf (linear dest, swizzled source)
    auto stage_w = [&](int n, float* buf) {
        const float4* wt = wtile0 + (size_t)n * II * 32;
#pragma unroll
        for (int j = 0; j < 8; ++j) {
            int row = lrow + 2 * j;
            int chunk = row * 32 + (lc ^ (row & 7));
            __builtin_amdgcn_global_load_lds(
                (const __attribute__((address_space(1))) void*)(wt + chunk),
                (__attribute__((address_space(3))) void*)(buf + j * 256),
                16, 0, 0);
        }
    };

    stage_w(0, &wlds[wv][0][0]);

    float xv[4][8];
#pragma unroll
    for (int bb = 0; bb < 4; ++bb) {
        const float4* xp = (const float4*)(xg + ((size_t)(b0 + bl + bb) * II + i) * KK);
        float4 x0 = xp[0], x1 = xp[1];
        xv[bb][0] = x0.x; xv[bb][1] = x0.y; xv[bb][2] = x0.z; xv[bb][3] = x0.w;
        xv[bb][4] = x1.x; xv[bb][5] = x1.y; xv[bb][6] = x1.z; xv[bb][7] = x1.w;
    }

#pragma unroll
    for (int n = 0; n < NN; ++n) {
        float* buf = &wlds[wv][n & 1][0];
        asm volatile("s_waitcnt vmcnt(0)" ::: "memory");   // buf landed
        float4 w[8];
#pragma unroll
        for (int jj = 0; jj < 8; ++jj)
            w[jj] = *(const float4*)(buf + il * 128 + dq * 32 + ((jj ^ (il & 7)) << 2));
        asm volatile("s_waitcnt lgkmcnt(0)" ::: "memory"); // reads done
        if (n < NN - 1) stage_w(n + 1, &wlds[wv][(n + 1) & 1][0]);

        float s[4][4];   // [bb][dj], value index j = bb*4+dj
#pragma unroll
        for (int dj = 0; dj < 4; ++dj) {
            float4 wa = w[2 * dj], wb = w[2 * dj + 1];
#pragma unroll
            for (int bb = 0; bb < 4; ++bb) {
                s[bb][dj] = wa.x * xv[bb][0] + wa.y * xv[bb][1]
                          + wa.z * xv[bb][2] + wa.w * xv[bb][3]
                          + wb.x * xv[bb][4] + wb.y * xv[bb][5]
                          + wb.z * xv[bb][6] + wb.w * xv[bb][7];
            }
        }
        // store u (bf16): wave-contiguous 512 B per (b,n)
#pragma unroll
        for (int bb = 0; bb < 4; ++bb) {
            uint2 q;
            q.x = pkbf(s[bb][0], s[bb][1]);
            q.y = pkbf(s[bb][2], s[bb][3]);
            *(uint2*)(u + (((size_t)(bl + bb) * NN + n) * II + i) * DD + dq * 4) = q;
        }
        // value-split butterfly over il lanes (masks 4,8,16,32)
        float v8[8];
#pragma unroll
        for (int k = 0; k < 8; ++k) {
            float a0 = s[(2 * k) >> 2][(2 * k) & 3];
            float a1 = s[(2 * k + 1) >> 2][(2 * k + 1) & 3];
            float give = h0 ? a0 : a1;
            float got  = __shfl_xor(give, 4, 64);
            v8[k] = (h0 ? a1 : a0) + got;
        }
        float v4[4];
#pragma unroll
        for (int k = 0; k < 4; ++k) {
            float a0 = v8[2 * k], a1 = v8[2 * k + 1];
            float give = h1 ? a0 : a1;
            float got  = __shfl_xor(give, 8, 64);
            v4[k] = (h1 ? a1 : a0) + got;
        }
        float v2[2];
#pragma unroll
        for (int k = 0; k < 2; ++k) {
            float a0 = v4[2 * k], a1 = v4[2 * k + 1];
            float give = h2 ? a0 : a1;
            float got  = __shfl_xor(give, 16, 64);
            v2[k] = (h2 ? a1 : a0) + got;
        }
        {
            float a0 = v2[0], a1 = v2[1];
            float give = h3 ? a0 : a1;
            float got  = __shfl_xor(give, 32, 64);
            myred[n] = (h3 ? a1 : a0) + got;   // ds_write_b32, exclusive slot
        }
    }

    __syncthreads();
#pragma unroll
    for (int idx = tid; idx < 640; idx += 256) {
        int bb = idx / 160, r = idx - bb * 160;
        int n = r >> 4, d = r & 15;
        int lane2 = ((bb * 4 + (d & 3)) << 2) + (d >> 2);   // il=bb*4+dj, dq=d>>2
        float v = redn[0][lane2][n] + redn[1][lane2][n]
                + redn[2][lane2][n] + redn[3][lane2][n];
        part0[((size_t)(b0 + bl + bb) * NT + it) * 160 + r] = 0.1f * v;
    }
}

// ---------------- fused routing: both sweeps + output, one block per b ------
// (byte-identical to R16, the proven 54us form)
// 1024 thr = 16 waves. Each i handled by an 8-lane group: ld = d-quad,
// hh = n-half (5 n's per lane, <=64 VGPR). 128 i/round x 9 rounds = 1152.
__global__ __launch_bounds__(1024) void caps_route(const ushort_t* __restrict__ u,
                                                   const float* __restrict__ p0,
                                                   float* __restrict__ out, int b0)
{
    __shared__ float red[16][8][20];    // 10,240 B
    __shared__ float o_s[160];
    __shared__ float s_s[160];
    const int tid = threadIdx.x;
    const int gi = tid >> 3;            // i-group 0..127
    const int gl = tid & 7;             // lane within group
    const int ld = gl & 3, hh = gl >> 2;
    const int wv = tid >> 6, lane = tid & 63;
    const int b = b0 + blockIdx.x;
    const ushort_t* ub = u + (size_t)blockIdx.x * (NN * II * DD);
    const ushort_t* ubh = ub + ((size_t)(hh * NH) * II + gi) * DD + ld * 4;

#define ULOAD(R, S)                                                            \
    _Pragma("unroll")                                                          \
    for (int k = 0; k < NH; ++k)                                               \
        R[k] = *(const uint2*)(ubh + ((size_t)k * II + (S) * 128) * DD);

#define STEP(R)                                                                \
    {                                                                          \
        float p[NH];                                                           \
        _Pragma("unroll")                                                      \
        for (int k = 0; k < NH; ++k) {                                         \
            float4 o4 = *(const float4*)&o_s[hh * 80 + k * 16 + ld * 4];       \
            p[k] = bflo(R[k].x) * o4.x + bfhi(R[k].x) * o4.y                   \
                 + bflo(R[k].y) * o4.z + bfhi(R[k].y) * o4.w;                  \
        }                                                                      \
        float a[NH];                                                           \
        _Pragma("unroll")                                                      \
        for (int k = 0; k < NH; ++k) {                                         \
            float t2 = p[k] + __shfl_xor(p[k], 1, 64);                         \
            a[k] = t2 + __shfl_xor(t2, 2, 64);                                 \
        }                                                                      \
        float mo = fmaxf(fmaxf(fmaxf(a[0], a[1]), fmaxf(a[2], a[3])), a[4]);   \
        float mx = fmaxf(mo, __shfl_xor(mo, 4, 64));                           \
        float c[NH];                                                           \
        _Pragma("unroll")                                                      \
        for (int k = 0; k < NH; ++k) c[k] = __expf(a[k] - mx);                 \
        float so = ((c[0] + c[1]) + (c[2] + c[3])) + c[4];                     \
        float ssum = so + __shfl_xor(so, 4, 64);                               \
        float inv = 1.0f / ssum;                                               \
        _Pragma("unroll")                                                      \
        for (int k = 0; k < NH; ++k) {                                         \
            float w = c[k] * inv;                                              \
            sp[k][0] += w * bflo(R[k].x); sp[k][1] += w * bfhi(R[k].x);        \
            sp[k][2] += w * bflo(R[k].y); sp[k][3] += w * bfhi(R[k].y);        \
        }                                                                      \
    }

#define PASS                                                                   \
    {                                                                          \
        uint2 rA[NH], rB[NH];                                                  \
        ULOAD(rA, 0)                                                           \
        ULOAD(rB, 1)  STEP(rA)                                                 \
        ULOAD(rA, 2)  STEP(rB)                                                 \
        ULOAD(rB, 3)  STEP(rA)                                                 \
        ULOAD(rA, 4)  STEP(rB)                                                 \
        ULOAD(rB, 5)  STEP(rA)                                                 \
        ULOAD(rA, 6)  STEP(rB)                                                 \
        ULOAD(rB, 7)  STEP(rA)                                                 \
        ULOAD(rA, 8)  STEP(rB)                                                 \
        STEP(rA)                                                               \
    }

#define BLOCK_REDUCE(DST)                                                      \
    {                                                                          \
        _Pragma("unroll")                                                      \
        for (int m = 8; m <= 32; m <<= 1)                                      \
            _Pragma("unroll")                                                  \
            for (int k = 0; k < NH; ++k)                                       \
                _Pragma("unroll")                                              \
                for (int j = 0; j < 4; ++j)                                    \
                    sp[k][j] += __shfl_xor(sp[k][j], m, 64);                   \
        if (lane < 8) {                                                        \
            _Pragma("unroll")                                                  \
            for (int k = 0; k < NH; ++k)                                       \
                _Pragma("unroll")                                              \
                for (int j = 0; j < 4; ++j)                                    \
                    red[wv][lane][k * 4 + j] = sp[k][j];                       \
        }                                                                      \
        __syncthreads();                                                       \
        if (tid < 160) {                                                       \
            int n = tid >> 4, d = tid & 15;                                    \
            int h2 = (n >= NH), k2 = n - h2 * NH;                              \
            int l8 = h2 * 4 + (d >> 2), j2 = d & 3;                            \
            float v = 0.f;                                                     \
            _Pragma("unroll")                                                  \
            for (int w = 0; w < 16; ++w) v += red[w][l8][k2 * 4 + j2];         \
            DST[tid] = v;                                                      \
        }                                                                      \
        __syncthreads();                                                       \
    }

    // ---- o1 = squash(sum_{NT} part0) ----
    if (tid < 160) {
        float v = 0.f;
#pragma unroll
        for (int t = 0; t < NT; ++t)
            v += p0[((size_t)b * NT + t) * 160 + tid];
        float sq = v * v;
#pragma unroll
        for (int m = 1; m <= 8; m <<= 1) sq += __shfl_xor(sq, m, 64);
        o_s[tid] = v * (sqrtf(sq) / (1.0f + sq));
    }
    __syncthreads();

    float sp[NH][4];
#pragma unroll
    for (int k = 0; k < NH; ++k)
#pragma unroll
        for (int j = 0; j < 4; ++j) sp[k][j] = 0.f;

    PASS                                     // pass 1 (o = o1)
    BLOCK_REDUCE(s_s)                        // s_s = sum c*u

    if (tid < 160) {                         // o2 = o1 + squash(s1)
        float v = s_s[tid];
        float sq = v * v;
#pragma unroll
        for (int m = 1; m <= 8; m <<= 1) sq += __shfl_xor(sq, m, 64);
        o_s[tid] = o_s[tid] + v * (sqrtf(sq) / (1.0f + sq));
    }
    __syncthreads();

#pragma unroll
    for (int k = 0; k < NH; ++k)
#pragma unroll
        for (int j = 0; j < 4; ++j) sp[k][j] = 0.f;

    PASS                                     // pass 2 (o = o1 + o2)
    BLOCK_REDUCE(s_s)

    if (tid < 160) {                         // out = squash(s2)
        float v = s_s[tid];
        float sq = v * v;
#pragma unroll
        for (int m = 1; m <= 8; m <<= 1) sq += __shfl_xor(sq, m, 64);
        out[(size_t)b * 160 + tid] = v * (sqrtf(sq) / (1.0f + sq));
    }
#undef ULOAD
#undef STEP
#undef PASS
#undef BLOCK_REDUCE
}

extern "C" void kernel_launch(void* const* d_in, const int* in_sizes, int n_in,
                              void* d_out, int out_size, void* d_ws, size_t ws_size,
                              hipStream_t stream)
{
    const float* xg = (const float*)d_in[0];  // [B,I,K]
    const float* wg = (const float*)d_in[1];  // [N,I,D,K]
    if (n_in >= 2 && in_sizes[0] == NN * II * DD * KK) {
        const float* t = xg; xg = wg; wg = t;
    }
    float* outp = (float*)d_out;

    const size_t perB  = (size_t)NN * II * DD * 2;       // 368,640 B bf16 u per b
    const size_t p0B   = (size_t)BN * NT * 160 * 4;      // 2,949,120
    size_t extra = p0B;
    size_t avail = (ws_size > extra) ? ws_size - extra : 0;
    int C = 256;
    if (avail < (size_t)256 * perB) {
        C = (int)(avail / perB);
        C &= ~15;
        if (C < 16) C = 16;
    }
    ushort_t* uws = (ushort_t*)d_ws;
    float* part0 = (float*)((char*)d_ws + (size_t)C * perB);

    for (int b0 = 0; b0 < BN; b0 += C) {
        int c = (BN - b0 < C) ? (BN - b0) : C;
        int c4 = c / 4;
        caps_uhat_s0<<<NT * c4, 256, 0, stream>>>(xg, wg, uws, part0, b0, c4);
        caps_route  <<<c, 1024, 0, stream>>>(uws, part0, outp, b0);
    }
}

// Round 15
// 137.085 us; speedup vs baseline: 1.0697x; 1.0697x over previous
//
#include <hip/hip_runtime.h>
#include <hip/hip_bf16.h>
#include <stdint.h>

// CapsuleLayer dynamic routing, MI355X. fp32 in/out.
// B=256, N=10, I=1152, D=16, K(Din)=8, ROUTINGS=3.
// R20 = R13 verbatim (the empirical best: 136.6us).
//  Ledger: R13 136.6 < R16 141.0 (fused route) < R18 142.6 < R19 146.6 <
//  R17 148.1. The fused-route arc never beat R13's split sweeps with
//  depth-2 rolling prefetch + tree max/sum. K1 is at a proven pipe
//  equilibrium (~44us; occupancy/conflicts/BW/store-drain all ruled out).
//  ~43us of the total is the harness workspace re-poison fill (on-stream,
//  not controllable). Locking in the best-known configuration.

#define BN 256
#define NN 10
#define II 1152
#define DD 16
#define KK 8
#define NT 18          // K1 i-tiles of 64
#define NP 5           // K1 n-pairs per i-tile
#define NCH 3          // sweep chunks
#define CHI 384        // i per sweep chunk (6 steps of 64)

typedef unsigned short ushort_t;
typedef unsigned int uint_t;

__device__ __forceinline__ float bflo(uint_t u) {
    union { uint_t i; float f; } v; v.i = u << 16; return v.f;
}
__device__ __forceinline__ float bfhi(uint_t u) {
    union { uint_t i; float f; } v; v.i = u & 0xffff0000u; return v.f;
}
// packed f32x2 -> bf16x2 (RTNE) via v_cvt_pk_bf16_f32
__device__ __forceinline__ uint_t pkbf(float lo, float hi) {
    __hip_bfloat162 h = __float22bfloat162_rn(make_float2(lo, hi));
    uint_t u; __builtin_memcpy(&u, &h, sizeof(u)); return u;
}

// ---------------- K1 + sweep0 partials --------------------------------------
// block = (i-tile of 64, n-pair, b-quad). 256 thr = 4 waves.
// lane = il*4+dq: thread owns (i = it*64 + wv*16 + il, d-quad dq), 4 b's,
// 2 consecutive n. XCD-colocation swizzle keeps each XCD's W slice
// L2-resident. Per wave per n, the 8KB W tile (16 rows x 512B) is staged:
//   global_load_lds j=0..7: lane l writes LDS linear l*16+j*1024; source
//   chunk = row*32 + ((l&31) ^ (row&7)), row = (l>>5)+2j  [XOR involution]
//   ds_read: lane (il,dq) frag jj at float idx il*128+dq*32+((jj^(il&7))<<2)
//   (jj is COMPILE-TIME: w[jj] static -> stays in VGPRs; rule #20)
// Reduction over il lanes: value-split butterfly (15 shfl per n).
// part0[b][it][n*16+d] = 0.1 * sum_{i in tile} u  (fp32, pre-pack values).
__global__ __launch_bounds__(256) void caps_uhat_s0(const float* __restrict__ xg,
                                                    const float* __restrict__ wg,
                                                    ushort_t* __restrict__ u,
                                                    float* __restrict__ part0,
                                                    int b0, int c4)
{
    __shared__ float wlds[4][2048];     // per-wave 8 KB W stage, 32 KB
    __shared__ float redn[4][64][2];    // [wv][lane][nn], 2 KB
    const int tid = threadIdx.x;
    const int lane = tid & 63, wv = tid >> 6;
    const int dq = lane & 3, il = lane >> 2;
    // grid = 90*c4, c4 multiple of 4 -> divisible by 8
    const int nb8 = gridDim.x >> 3;
    const int L   = (blockIdx.x & 7) * nb8 + (blockIdx.x >> 3);
    const int it  = L / (NP * c4);
    const int rem = L - it * (NP * c4);
    const int np  = rem / c4;
    const int bl  = (rem - np * c4) * 4;       // chunk-local b base (4 b's)
    const int n0  = np * 2;
    const int i = it * 64 + wv * 16 + il;

    const bool h0 = (il & 1), h1 = (il >> 1) & 1, h2 = (il >> 2) & 1, h3 = (il >> 3) & 1;
    float* myred = &redn[wv][lane][0];
    float* mylds = &wlds[wv][0];
    const int lrow = lane >> 5, lc = lane & 31;
    const float4* wtile0 = (const float4*)(wg + (size_t)(n0 * II + it * 64 + wv * 16) * (DD * KK));

#define STAGE_W(NNV)                                                         \
    {                                                                        \
        const float4* wt = wtile0 + (size_t)(NNV) * II * 32;                 \
        _Pragma("unroll")                                                    \
        for (int j = 0; j < 8; ++j) {                                        \
            int row = lrow + 2 * j;                                          \
            int chunk = row * 32 + (lc ^ (row & 7));                         \
            __builtin_amdgcn_global_load_lds(                                \
                (const __attribute__((address_space(1))) void*)(wt + chunk), \
                (__attribute__((address_space(3))) void*)(mylds + j * 256),  \
                16, 0, 0);                                                   \
        }                                                                    \
    }

    STAGE_W(0);

    float xv[4][8];
#pragma unroll
    for (int bb = 0; bb < 4; ++bb) {
        const float4* xp = (const float4*)(xg + ((size_t)(b0 + bl + bb) * II + i) * KK);
        float4 x0 = xp[0], x1 = xp[1];
        xv[bb][0] = x0.x; xv[bb][1] = x0.y; xv[bb][2] = x0.z; xv[bb][3] = x0.w;
        xv[bb][4] = x1.x; xv[bb][5] = x1.y; xv[bb][6] = x1.z; xv[bb][7] = x1.w;
    }

    auto compute_n = [&](int n, const float4* w, int slot) {
        float s[4][4];   // [bb][dj], value index j = bb*4+dj
#pragma unroll
        for (int dj = 0; dj < 4; ++dj) {
            float4 wa = w[2 * dj], wb = w[2 * dj + 1];
#pragma unroll
            for (int bb = 0; bb < 4; ++bb) {
                s[bb][dj] = wa.x * xv[bb][0] + wa.y * xv[bb][1]
                          + wa.z * xv[bb][2] + wa.w * xv[bb][3]
                          + wb.x * xv[bb][4] + wb.y * xv[bb][5]
                          + wb.z * xv[bb][6] + wb.w * xv[bb][7];
            }
        }
        // store u (bf16): wave-contiguous 512 B per (b,n)
#pragma unroll
        for (int bb = 0; bb < 4; ++bb) {
            uint2 q;
            q.x = pkbf(s[bb][0], s[bb][1]);
            q.y = pkbf(s[bb][2], s[bb][3]);
            *(uint2*)(u + (((size_t)(bl + bb) * NN + n) * II + i) * DD + dq * 4) = q;
        }
        // value-split butterfly over il lanes (masks 4,8,16,32)
        float v8[8];
#pragma unroll
        for (int k = 0; k < 8; ++k) {
            float a0 = s[(2 * k) >> 2][(2 * k) & 3];
            float a1 = s[(2 * k + 1) >> 2][(2 * k + 1) & 3];
            float give = h0 ? a0 : a1;
            float got  = __shfl_xor(give, 4, 64);
            v8[k] = (h0 ? a1 : a0) + got;
        }
        float v4[4];
#pragma unroll
        for (int k = 0; k < 4; ++k) {
            float a0 = v8[2 * k], a1 = v8[2 * k + 1];
            float give = h1 ? a0 : a1;
            float got  = __shfl_xor(give, 8, 64);
            v4[k] = (h1 ? a1 : a0) + got;
        }
        float v2[2];
#pragma unroll
        for (int k = 0; k < 2; ++k) {
            float a0 = v4[2 * k], a1 = v4[2 * k + 1];
            float give = h2 ? a0 : a1;
            float got  = __shfl_xor(give, 16, 64);
            v2[k] = (h2 ? a1 : a0) + got;
        }
        {
            float a0 = v2[0], a1 = v2[1];
            float give = h3 ? a0 : a1;
            float got  = __shfl_xor(give, 32, 64);
            myred[slot] = (h3 ? a1 : a0) + got;   // ds_write_b32, exclusive slot
        }
    };

    float4 w[8];
    // n0: wait staging (and x), read fragments (swizzled), free buffer, stage n1
    asm volatile("s_waitcnt vmcnt(0)" ::: "memory");
#pragma unroll
    for (int jj = 0; jj < 8; ++jj)
        w[jj] = *(const float4*)(mylds + il * 128 + dq * 32 + ((jj ^ (il & 7)) << 2));
    asm volatile("s_waitcnt lgkmcnt(0)" ::: "memory");   // reads done -> buffer free
    STAGE_W(1);
    compute_n(n0, w, 0);

    // n1
    asm volatile("s_waitcnt vmcnt(0)" ::: "memory");
#pragma unroll
    for (int jj = 0; jj < 8; ++jj)
        w[jj] = *(const float4*)(mylds + il * 128 + dq * 32 + ((jj ^ (il & 7)) << 2));
    compute_n(n0 + 1, w, 1);
#undef STAGE_W

    __syncthreads();
    if (tid < 128) {
        int bb = tid >> 5, r5 = tid & 31, nn = r5 >> 4, d = r5 & 15;
        int lane2 = ((bb * 4 + (d & 3)) << 2) + (d >> 2);   // il=bb*4+dj, dq=d>>2
        float v = redn[0][lane2][nn] + redn[1][lane2][nn]
                + redn[2][lane2][nn] + redn[3][lane2][nn];
        part0[((size_t)(b0 + bl + bb) * NT + it) * 160 + (n0 + nn) * 16 + d] = 0.1f * v;
    }
}

// ---- block reduction of sp[NN][4] over 64 groups -> 160 floats -------------
__device__ __forceinline__ void block_reduce_part(float sp[NN][4], int tid,
                                                  float* red,
                                                  float* __restrict__ partp)
{
#pragma unroll
    for (int m = 4; m <= 32; m <<= 1)
#pragma unroll
        for (int n = 0; n < NN; ++n)
#pragma unroll
            for (int j = 0; j < 4; ++j)
                sp[n][j] += __shfl_xor(sp[n][j], m, 64);

    const int lane = tid & 63, wv = tid >> 6, ld = tid & 3;
    if (lane < 4) {
#pragma unroll
        for (int n = 0; n < NN; ++n)
#pragma unroll
            for (int j = 0; j < 4; ++j)
                red[(wv * NN + n) * 16 + ld * 4 + j] = sp[n][j];
    }
    __syncthreads();
    if (tid < 160) {
        int n = tid >> 4, dd = tid & 15;
        float v = 0.f;
#pragma unroll
        for (int w = 0; w < 4; ++w) v += red[(w * NN + n) * 16 + dd];
        partp[tid] = v;
    }
}

// ---------------- sweep r=1,2 ----------------------------------------------
// o = squash(sum_{18} part0[b]);  if p1: o += squash(sum_{3} p1[b]).
// c = softmax_n(<o,u>), partial s = sum c*u over this 384-i chunk.
// Depth-2 rolling prefetch: rA/rB/rC rotated by NAME (static indexing only).
__global__ __launch_bounds__(256) void caps_sweep(const ushort_t* __restrict__ u,
                                                  const float* __restrict__ p0,
                                                  const float* __restrict__ p1,
                                                  float* __restrict__ pout, int b0)
{
    __shared__ float red[4 * 160];
    __shared__ float o_s[160];
    const int tid = threadIdx.x, g = tid >> 2, ld = tid & 3;
    const int cb = blockIdx.x / NCH, ch = blockIdx.x % NCH;
    const int b = b0 + cb;
    const ushort_t* ub = u + (size_t)cb * (NN * II * DD);
    const int i0 = ch * CHI + g;

#define ULOAD(R, S)                                                            \
    _Pragma("unroll")                                                          \
    for (int n = 0; n < NN; ++n)                                               \
        R[n] = *(const uint2*)(ub + ((size_t)(n * II + i0 + (S) * 64)) * DD + ld * 4);

    uint2 rA[NN], rB[NN], rC[NN];
    ULOAD(rA, 0)
    ULOAD(rB, 1)

    if (tid < 160) {
        float v = 0.f;
#pragma unroll
        for (int t = 0; t < NT; ++t)
            v += p0[((size_t)b * NT + t) * 160 + tid];
        float sq = v * v;
#pragma unroll
        for (int m = 1; m <= 8; m <<= 1) sq += __shfl_xor(sq, m, 64);
        float o = v * (sqrtf(sq) / (1.0f + sq));
        if (p1) {
            float v1 = 0.f;
#pragma unroll
            for (int c2 = 0; c2 < NCH; ++c2)
                v1 += p1[((size_t)b * NCH + c2) * 160 + tid];
            float sq1 = v1 * v1;
#pragma unroll
            for (int m = 1; m <= 8; m <<= 1) sq1 += __shfl_xor(sq1, m, 64);
            o += v1 * (sqrtf(sq1) / (1.0f + sq1));
        }
        o_s[tid] = o;
    }
    __syncthreads();

    float sp[NN][4];
#pragma unroll
    for (int n = 0; n < NN; ++n)
#pragma unroll
        for (int j = 0; j < 4; ++j) sp[n][j] = 0.f;

#define STEP(R)                                                                \
    {                                                                          \
        float p[NN];                                                           \
        _Pragma("unroll")                                                      \
        for (int n = 0; n < NN; ++n) {                                         \
            float4 o4 = *(const float4*)&o_s[(n << 4) + (ld << 2)];            \
            p[n] = bflo(R[n].x) * o4.x + bfhi(R[n].x) * o4.y                   \
                 + bflo(R[n].y) * o4.z + bfhi(R[n].y) * o4.w;                  \
        }                                                                      \
        float a[NN];                                                           \
        _Pragma("unroll")                                                      \
        for (int n = 0; n < NN; ++n) {                                         \
            float t2 = p[n] + __shfl_xor(p[n], 1, 64);                         \
            a[n] = t2 + __shfl_xor(t2, 2, 64);                                 \
        }                                                                      \
        float m01 = fmaxf(fmaxf(a[0], a[1]), a[2]);                            \
        float m2  = fmaxf(fmaxf(a[3], a[4]), a[5]);                            \
        float m3  = fmaxf(fmaxf(a[6], a[7]), a[8]);                            \
        float mx  = fmaxf(fmaxf(m01, m2), fmaxf(m3, a[9]));                    \
        float c[NN];                                                           \
        _Pragma("unroll")                                                      \
        for (int n = 0; n < NN; ++n) c[n] = __expf(a[n] - mx);                 \
        float s01 = c[0] + c[1], s23 = c[2] + c[3], s45 = c[4] + c[5];         \
        float s67 = c[6] + c[7], s89 = c[8] + c[9];                            \
        float ssum = ((s01 + s23) + (s45 + s67)) + s89;                        \
        float inv = 1.0f / ssum;                                               \
        _Pragma("unroll")                                                      \
        for (int n = 0; n < NN; ++n) {                                         \
            float w = c[n] * inv;                                              \
            sp[n][0] += w * bflo(R[n].x); sp[n][1] += w * bfhi(R[n].x);        \
            sp[n][2] += w * bflo(R[n].y); sp[n][3] += w * bfhi(R[n].y);        \
        }                                                                      \
    }

    ULOAD(rC, 2)  STEP(rA)
    ULOAD(rA, 3)  STEP(rB)
    ULOAD(rB, 4)  STEP(rC)
    ULOAD(rC, 5)  STEP(rA)
    STEP(rB)
    STEP(rC)
#undef ULOAD
#undef STEP

    block_reduce_part(sp, tid, red, pout + ((size_t)b * NCH + ch) * 160);
}

// ---------------- output: squash(sum_ch part2) ------------------------------
__global__ __launch_bounds__(192) void caps_out(const float* __restrict__ p2,
                                                float* __restrict__ out, int b0)
{
    const int b = b0 + blockIdx.x;
    const int t = threadIdx.x;
    if (t < 160) {
        float v = 0.f;
#pragma unroll
        for (int ch = 0; ch < NCH; ++ch)
            v += p2[((size_t)b * NCH + ch) * 160 + t];
        float sq = v * v;
#pragma unroll
        for (int m = 1; m <= 8; m <<= 1) sq += __shfl_xor(sq, m, 64);
        out[(size_t)b * 160 + t] = v * (sqrtf(sq) / (1.0f + sq));
    }
}

extern "C" void kernel_launch(void* const* d_in, const int* in_sizes, int n_in,
                              void* d_out, int out_size, void* d_ws, size_t ws_size,
                              hipStream_t stream)
{
    const float* xg = (const float*)d_in[0];  // [B,I,K]
    const float* wg = (const float*)d_in[1];  // [N,I,D,K]
    if (n_in >= 2 && in_sizes[0] == NN * II * DD * KK) {
        const float* t = xg; xg = wg; wg = t;
    }
    float* outp = (float*)d_out;

    const size_t perB  = (size_t)NN * II * DD * 2;       // 368,640 B bf16 u per b
    const size_t p0B   = (size_t)BN * NT * 160 * 4;      // 2,949,120
    const size_t p12B  = (size_t)BN * NCH * 160 * 4;     // 491,520 each
    size_t extra = p0B + 2 * p12B;
    size_t avail = (ws_size > extra) ? ws_size - extra : 0;
    int C = 256;
    if (avail < (size_t)256 * perB) {
        C = (int)(avail / perB);
        C &= ~15;
        if (C < 16) C = 16;
    }
    ushort_t* uws = (ushort_t*)d_ws;
    float* part0 = (float*)((char*)d_ws + (size_t)C * perB);
    float* part1 = part0 + (size_t)BN * NT * 160;
    float* part2 = part1 + (size_t)BN * NCH * 160;

    for (int b0 = 0; b0 < BN; b0 += C) {
        int c = (BN - b0 < C) ? (BN - b0) : C;
        int c4 = c / 4;
        caps_uhat_s0<<<NT * NP * c4, 256, 0, stream>>>(xg, wg, uws, part0, b0, c4);
        caps_sweep  <<<c * NCH, 256, 0, stream>>>(uws, part0, nullptr, part1, b0);
        caps_sweep  <<<c * NCH, 256, 0, stream>>>(uws, part0, part1,  part2, b0);
        caps_out    <<<c,       192, 0, stream>>>(part2, outp, b0);
    }
}